// Round 1
// baseline (3049.390 us; speedup 1.0000x reference)
//
#include <hip/hip_runtime.h>
#include <hip/hip_bf16.h>

#define LTOT 4096
#define DM 256
#define BATCH 8
#define NH 8
#define DH 32
#define MROWS (BATCH * LTOT)  // 32768

__device__ __forceinline__ float elu1(float x) {
    return x > 0.f ? x + 1.f : expf(x);
}

// ---------------------------------------------------------------------------
// prep: X[b, l, c] = feats[b, c, l] + pos_encoding(c, l)   (32x32 LDS transpose)
// ---------------------------------------------------------------------------
__global__ __launch_bounds__(256) void prep_kernel(const float* __restrict__ feats,
                                                   float* __restrict__ X) {
    __shared__ float tile[32][33];
    int b = blockIdx.z;
    int l0 = blockIdx.x * 32;
    int c0 = blockIdx.y * 32;
    int tx = threadIdx.x;  // 0..31
    int ty = threadIdx.y;  // 0..7
#pragma unroll
    for (int j = 0; j < 4; ++j) {
        int c = c0 + ty + j * 8;
        tile[ty + j * 8][tx] = feats[((size_t)(b * DM + c)) * LTOT + l0 + tx];
    }
    __syncthreads();
#pragma unroll
    for (int j = 0; j < 4; ++j) {
        int l = l0 + ty + j * 8;
        int c = c0 + tx;
        // pos encoding: div = exp(2*(c/4) * (-ln(10000)/128))
        int i2 = (c >> 2) * 2;
        float dv = expf((float)i2 * -0.07195578415156063f);
        int rem = c & 3;
        int y = l >> 6, xc = l & 63;
        float pos = (rem < 2) ? (float)(xc + 1) : (float)(y + 1);
        float arg = pos * dv;
        float pe = (rem & 1) ? cosf(arg) : sinf(arg);
        X[((size_t)(b * LTOT + l)) * DM + c] = tile[tx][ty + j * 8] + pe;
    }
}

// ---------------------------------------------------------------------------
// unprep: out[b, c, l] = X[b, l, c]
// ---------------------------------------------------------------------------
__global__ __launch_bounds__(256) void unprep_kernel(const float* __restrict__ X,
                                                     float* __restrict__ out) {
    __shared__ float tile[32][33];
    int b = blockIdx.z;
    int l0 = blockIdx.x * 32;
    int c0 = blockIdx.y * 32;
    int tx = threadIdx.x;
    int ty = threadIdx.y;
#pragma unroll
    for (int j = 0; j < 4; ++j) {
        int l = l0 + ty + j * 8;
        tile[ty + j * 8][tx] = X[((size_t)(b * LTOT + l)) * DM + c0 + tx];  // [l_local][c_local]
    }
    __syncthreads();
#pragma unroll
    for (int j = 0; j < 4; ++j) {
        int c = c0 + ty + j * 8;
        out[((size_t)(b * DM + c)) * LTOT + l0 + tx] = tile[tx][ty + j * 8];
    }
}

// ---------------------------------------------------------------------------
// fp32 GEMM: C[M,N] = act( (BETA ? C : 0) + A[M,K] @ W[K,N] )
// 64x64 block tile, 256 threads, 4x4 microtile, K-tile 16.
// ACT: 0 none, 1 elu+1, 2 relu.
// ---------------------------------------------------------------------------
template <int ACT, int BETA>
__global__ __launch_bounds__(256) void gemm_f32(const float* __restrict__ A,
                                                const float* __restrict__ W,
                                                float* __restrict__ C, int N, int K) {
    __shared__ float As[16][68];  // [k][m], pad 68 -> 16B-aligned rows, ~2-way banks
    __shared__ float Bs[16][68];  // [k][n]
    int tid = threadIdx.x;
    int m0 = blockIdx.x * 64;
    int n0 = blockIdx.y * 64;
    int tx = tid & 15, ty = tid >> 4;
    int arow = tid >> 2, acol = (tid & 3) * 4;
    int brow = tid >> 4, bcol = (tid & 15) * 4;
    const float* Ap = A + (size_t)(m0 + arow) * K + acol;
    const float* Wp = W + (size_t)brow * N + n0 + bcol;
    float acc[4][4] = {};
    for (int k0 = 0; k0 < K; k0 += 16) {
        float4 av = *(const float4*)(Ap + k0);
        float4 bv = *(const float4*)(Wp + (size_t)k0 * N);
        As[acol + 0][arow] = av.x;
        As[acol + 1][arow] = av.y;
        As[acol + 2][arow] = av.z;
        As[acol + 3][arow] = av.w;
        *(float4*)&Bs[brow][bcol] = bv;
        __syncthreads();
#pragma unroll
        for (int k = 0; k < 16; ++k) {
            float4 a = *(const float4*)&As[k][ty * 4];
            float4 b = *(const float4*)&Bs[k][tx * 4];
            acc[0][0] += a.x * b.x; acc[0][1] += a.x * b.y; acc[0][2] += a.x * b.z; acc[0][3] += a.x * b.w;
            acc[1][0] += a.y * b.x; acc[1][1] += a.y * b.y; acc[1][2] += a.y * b.z; acc[1][3] += a.y * b.w;
            acc[2][0] += a.z * b.x; acc[2][1] += a.z * b.y; acc[2][2] += a.z * b.z; acc[2][3] += a.z * b.w;
            acc[3][0] += a.w * b.x; acc[3][1] += a.w * b.y; acc[3][2] += a.w * b.z; acc[3][3] += a.w * b.w;
        }
        __syncthreads();
    }
#pragma unroll
    for (int i = 0; i < 4; ++i) {
        float* cp = C + (size_t)(m0 + ty * 4 + i) * N + n0 + tx * 4;
        float4 r = make_float4(acc[i][0], acc[i][1], acc[i][2], acc[i][3]);
        if (BETA) {
            float4 p = *(const float4*)cp;
            r.x += p.x; r.y += p.y; r.z += p.z; r.w += p.w;
        }
        if (ACT == 1) { r.x = elu1(r.x); r.y = elu1(r.y); r.z = elu1(r.z); r.w = elu1(r.w); }
        if (ACT == 2) {
            r.x = fmaxf(r.x, 0.f); r.y = fmaxf(r.y, 0.f);
            r.z = fmaxf(r.z, 0.f); r.w = fmaxf(r.w, 0.f);
        }
        *(float4*)cp = r;
    }
}

// ---------------------------------------------------------------------------
// zero scratch
// ---------------------------------------------------------------------------
__global__ void zero_kernel(float* __restrict__ p, int n) {
    int i = blockIdx.x * 256 + threadIdx.x;
    if (i < n) p[i] = 0.f;
}

// ---------------------------------------------------------------------------
// KV[b,h,d,v] = sum_s K[b,s,h,d] * V[b,s,h,v];  KS[b,h,d] = sum_s K[b,s,h,d]
// block: (bh, s_part of 512); 256 threads, thread owns (d, 4 v's); atomic combine.
// ---------------------------------------------------------------------------
__global__ __launch_bounds__(256) void kv_kernel(const float* __restrict__ Kf,
                                                 const float* __restrict__ Vf,
                                                 float* __restrict__ KV,
                                                 float* __restrict__ KS) {
    __shared__ float Ks[64][36];
    __shared__ float Vs[64][36];
    int tid = threadIdx.x;
    int bh = blockIdx.x;  // 0..63
    int sp = blockIdx.y;  // 0..7
    int b = bh >> 3, h = bh & 7;
    int d = tid >> 3, vb = (tid & 7) * 4;
    float acc0 = 0.f, acc1 = 0.f, acc2 = 0.f, acc3 = 0.f;
    float ksacc = 0.f;
    for (int s0 = sp * 512; s0 < sp * 512 + 512; s0 += 64) {
        for (int i = tid; i < 512; i += 256) {
            int r = i >> 3, c = (i & 7) * 4;
            size_t off = ((size_t)(b * LTOT + s0 + r)) * DM + h * DH + c;
            *(float4*)&Ks[r][c] = *(const float4*)(Kf + off);
            *(float4*)&Vs[r][c] = *(const float4*)(Vf + off);
        }
        __syncthreads();
#pragma unroll 8
        for (int s = 0; s < 64; ++s) {
            float kd = Ks[s][d];
            acc0 += kd * Vs[s][vb + 0];
            acc1 += kd * Vs[s][vb + 1];
            acc2 += kd * Vs[s][vb + 2];
            acc3 += kd * Vs[s][vb + 3];
        }
        if (tid < 32) {
#pragma unroll 8
            for (int s = 0; s < 64; ++s) ksacc += Ks[s][tid];
        }
        __syncthreads();
    }
    float* kvp = KV + (size_t)bh * 1024 + d * 32 + vb;
    atomicAdd(kvp + 0, acc0);
    atomicAdd(kvp + 1, acc1);
    atomicAdd(kvp + 2, acc2);
    atomicAdd(kvp + 3, acc3);
    if (tid < 32) atomicAdd(KS + bh * 32 + tid, ksacc);
}

// ---------------------------------------------------------------------------
// msg[b,l,h,v] = (sum_d Q[b,l,h,d]*KV[b,h,d,v]) / (sum_d Q[b,l,h,d]*KS[b,h,d] + eps)
// block: (l-chunk of 32, b); thread = (l_local, h).
// ---------------------------------------------------------------------------
__global__ __launch_bounds__(256) void msg_kernel(const float* __restrict__ Q,
                                                  const float* __restrict__ KV,
                                                  const float* __restrict__ KS,
                                                  float* __restrict__ Msg) {
    __shared__ float KVs[8 * 1032];  // per-head stride 1032 -> 2-way banks max
    __shared__ float KSs[256];
    int tid = threadIdx.x;
    int b = blockIdx.y;
    int l0 = blockIdx.x * 32;
    for (int i = tid; i < 8192; i += 256) {
        int h = i >> 10, r = i & 1023;
        KVs[h * 1032 + r] = KV[((size_t)(b * 8 + h)) * 1024 + r];
    }
    KSs[tid] = KS[b * 256 + tid];
    __syncthreads();
    int l = l0 + (tid >> 3);
    int h = tid & 7;
    const float* qp = Q + ((size_t)(b * LTOT + l)) * DM + h * DH;
    float qv[32];
#pragma unroll
    for (int i = 0; i < 8; ++i) {
        float4 q4 = *(const float4*)(qp + i * 4);
        qv[i * 4 + 0] = q4.x; qv[i * 4 + 1] = q4.y;
        qv[i * 4 + 2] = q4.z; qv[i * 4 + 3] = q4.w;
    }
    float den = 1e-6f;
#pragma unroll
    for (int d2 = 0; d2 < 32; ++d2) den += qv[d2] * KSs[h * 32 + d2];
    float rz = 1.f / den;
    float acc[32] = {};
#pragma unroll
    for (int d2 = 0; d2 < 32; ++d2) {
        float qd = qv[d2];
        const float* kvp = &KVs[h * 1032 + d2 * 32];
#pragma unroll
        for (int v = 0; v < 32; ++v) acc[v] += qd * kvp[v];
    }
    float* op = Msg + ((size_t)(b * LTOT + l)) * DM + h * DH;
#pragma unroll
    for (int i = 0; i < 8; ++i) {
        float4 o4 = make_float4(acc[i * 4 + 0] * rz, acc[i * 4 + 1] * rz,
                                acc[i * 4 + 2] * rz, acc[i * 4 + 3] * rz);
        *(float4*)(op + i * 4) = o4;
    }
}

// ---------------------------------------------------------------------------
// LayerNorm over last dim (256). One wave per row, 4 rows per block.
// RES=0: Out[row] = LN(In[row])      (in-place OK)
// RES=1: Out[row] += LN(In[row])     (residual accumulate into X)
// ---------------------------------------------------------------------------
template <int RES>
__global__ __launch_bounds__(256) void ln_kernel(const float* __restrict__ In,
                                                 const float* __restrict__ g,
                                                 const float* __restrict__ bta,
                                                 float* __restrict__ Out) {
    int row = blockIdx.x * 4 + (threadIdx.x >> 6);
    int lane = threadIdx.x & 63;
    int c = lane * 4;
    const float* p = In + (size_t)row * DM + c;
    float4 v = *(const float4*)p;
    float s = v.x + v.y + v.z + v.w;
#pragma unroll
    for (int o = 1; o < 64; o <<= 1) s += __shfl_xor(s, o, 64);
    float mu = s * (1.f / 256.f);
    float dx = v.x - mu, dy = v.y - mu, dz = v.z - mu, dw = v.w - mu;
    float sq = dx * dx + dy * dy + dz * dz + dw * dw;
#pragma unroll
    for (int o = 1; o < 64; o <<= 1) sq += __shfl_xor(sq, o, 64);
    float rstd = rsqrtf(sq * (1.f / 256.f) + 1e-5f);
    float4 gv = *(const float4*)(g + c);
    float4 bv = *(const float4*)(bta + c);
    float4 o4;
    o4.x = dx * rstd * gv.x + bv.x;
    o4.y = dy * rstd * gv.y + bv.y;
    o4.z = dz * rstd * gv.z + bv.z;
    o4.w = dw * rstd * gv.w + bv.w;
    float* op = Out + (size_t)row * DM + c;
    if (RES) {
        float4 x4 = *(const float4*)op;
        o4.x += x4.x; o4.y += x4.y; o4.z += x4.z; o4.w += x4.w;
    }
    *(float4*)op = o4;
}

// ---------------------------------------------------------------------------
// Orchestration
// ---------------------------------------------------------------------------
extern "C" void kernel_launch(void* const* d_in, const int* in_sizes, int n_in,
                              void* d_out, int out_size, void* d_ws, size_t ws_size,
                              hipStream_t stream) {
    const float* feats = (const float*)d_in[0];
    const float* Wq = (const float*)d_in[1];
    const float* Wk = (const float*)d_in[2];
    const float* Wv = (const float*)d_in[3];
    const float* Wm = (const float*)d_in[4];
    const float* W1 = (const float*)d_in[5];
    const float* W2 = (const float*)d_in[6];
    const float* g1 = (const float*)d_in[7];
    const float* b1 = (const float*)d_in[8];
    const float* g2 = (const float*)d_in[9];
    const float* b2 = (const float*)d_in[10];

    const size_t NX = (size_t)MROWS * DM;  // 8388608 floats
    float* ws = (float*)d_ws;
    float* X = ws;              // x (residual stream)
    float* A = X + NX;          // Q, later msg@Wm + LN1(msg)
    float* HB = A + NX;         // 2*NX floats: first NX = K feats; whole = MLP hidden
    float* KV = HB + 2 * NX;    // 8*8*32*32
    float* KS = KV + 65536;     // 8*8*32
    float* C = (float*)d_out;   // V, later msg, later msg2 (out_size == NX)

    dim3 tpgrid(128, 8, 8), tpblk(32, 8);
    dim3 g256(512, 4), g512(512, 8);

    prep_kernel<<<tpgrid, tpblk, 0, stream>>>(feats, X);

    for (int layer = 0; layer < 4; ++layer) {
        const float* wq = Wq + (size_t)layer * DM * DM;
        const float* wk = Wk + (size_t)layer * DM * DM;
        const float* wv = Wv + (size_t)layer * DM * DM;
        const float* wm = Wm + (size_t)layer * DM * DM;
        const float* w1 = W1 + (size_t)layer * 512 * 512;
        const float* w2 = W2 + (size_t)layer * 512 * 256;
        const float* lg1 = g1 + layer * DM;
        const float* lb1 = b1 + layer * DM;
        const float* lg2 = g2 + layer * DM;
        const float* lb2 = b2 + layer * DM;

        gemm_f32<1, 0><<<g256, 256, 0, stream>>>(X, wq, A, 256, 256);    // Q = elu(x@Wq)+1
        gemm_f32<1, 0><<<g256, 256, 0, stream>>>(X, wk, HB, 256, 256);   // K = elu(x@Wk)+1
        gemm_f32<0, 0><<<g256, 256, 0, stream>>>(X, wv, C, 256, 256);    // V = x@Wv
        zero_kernel<<<dim3((65536 + 2048 + 255) / 256), 256, 0, stream>>>(KV, 65536 + 2048);
        kv_kernel<<<dim3(64, 8), 256, 0, stream>>>(HB, C, KV, KS);
        msg_kernel<<<dim3(128, 8), 256, 0, stream>>>(A, KV, KS, C);      // C = msg
        gemm_f32<0, 0><<<g256, 256, 0, stream>>>(C, wm, A, 256, 256);    // A = msg@Wm
        ln_kernel<0><<<8192, 256, 0, stream>>>(A, lg1, lb1, A);          // A = LN1(A)
        gemm_f32<0, 0><<<g512, 256, 0, stream>>>(X, w1, HB, 512, 256);   // HB = x@W1[:256]
        gemm_f32<2, 1><<<g512, 256, 0, stream>>>(A, w1 + 256 * 512, HB, 512, 256);  // HB = relu(HB + A@W1[256:])
        gemm_f32<0, 0><<<g256, 256, 0, stream>>>(HB, w2, C, 256, 512);   // C = HB@W2
        ln_kernel<1><<<8192, 256, 0, stream>>>(C, lg2, lb2, X);          // X += LN2(C)
    }

    unprep_kernel<<<tpgrid, tpblk, 0, stream>>>(X, (float*)d_out);
}

// Round 2
// 860.059 us; speedup vs baseline: 3.5456x; 3.5456x over previous
//
#include <hip/hip_runtime.h>
#include <hip/hip_bf16.h>

#define LTOT 4096
#define DM 256
#define BATCH 8
#define MROWS (BATCH * LTOT)   // 32768
#define NX ((size_t)MROWS * DM)  // 8388608 elements

typedef __bf16 bf16x8 __attribute__((ext_vector_type(8)));
typedef float f32x4 __attribute__((ext_vector_type(4)));

__device__ __forceinline__ float elu1(float x) {
    return x > 0.f ? x + 1.f : expf(x);
}
__device__ __forceinline__ ushort f2bf(float f) {
    unsigned u = __float_as_uint(f);
    u += 0x7FFFu + ((u >> 16) & 1u);
    return (ushort)(u >> 16);
}
__device__ __forceinline__ float b2f(ushort u) {
    return __uint_as_float(((unsigned)u) << 16);
}

// ---------------------------------------------------------------------------
// prep: X[b,l,c] = feats[b,c,l] + pos(c,l)  (fp32) ; XC[b,l,c] = bf16(same),
// XC row stride 512 (left half of the [x | ln1msg] concat buffer).
// ---------------------------------------------------------------------------
__global__ __launch_bounds__(256) void prep_kernel(const float* __restrict__ feats,
                                                   float* __restrict__ X,
                                                   ushort* __restrict__ XC) {
    __shared__ float tile[32][33];
    int b = blockIdx.z;
    int l0 = blockIdx.x * 32;
    int c0 = blockIdx.y * 32;
    int tx = threadIdx.x, ty = threadIdx.y;
#pragma unroll
    for (int j = 0; j < 4; ++j) {
        int c = c0 + ty + j * 8;
        tile[ty + j * 8][tx] = feats[((size_t)(b * DM + c)) * LTOT + l0 + tx];
    }
    __syncthreads();
#pragma unroll
    for (int j = 0; j < 4; ++j) {
        int l = l0 + ty + j * 8;
        int c = c0 + tx;
        int i2 = (c >> 2) * 2;
        float dv = expf((float)i2 * -0.07195578415156063f);
        int rem = c & 3;
        int y = l >> 6, xc = l & 63;
        float pos = (rem < 2) ? (float)(xc + 1) : (float)(y + 1);
        float arg = pos * dv;
        float pe = (rem & 1) ? cosf(arg) : sinf(arg);
        float val = tile[tx][ty + j * 8] + pe;
        size_t row = (size_t)(b * LTOT + l);
        X[row * DM + c] = val;
        XC[row * 512 + c] = f2bf(val);
    }
}

__global__ __launch_bounds__(256) void unprep_kernel(const float* __restrict__ X,
                                                     float* __restrict__ out) {
    __shared__ float tile[32][33];
    int b = blockIdx.z;
    int l0 = blockIdx.x * 32;
    int c0 = blockIdx.y * 32;
    int tx = threadIdx.x, ty = threadIdx.y;
#pragma unroll
    for (int j = 0; j < 4; ++j) {
        int l = l0 + ty + j * 8;
        tile[ty + j * 8][tx] = X[((size_t)(b * LTOT + l)) * DM + c0 + tx];
    }
    __syncthreads();
#pragma unroll
    for (int j = 0; j < 4; ++j) {
        int c = c0 + ty + j * 8;
        out[((size_t)(b * DM + c)) * LTOT + l0 + tx] = tile[tx][ty + j * 8];
    }
}

// ---------------------------------------------------------------------------
// weight transpose + bf16 cast: WT[n][k] = bf16(W[k][n]); z = matrix index
// ---------------------------------------------------------------------------
__global__ __launch_bounds__(256) void wtrans_kernel(const float* __restrict__ W,
                                                     ushort* __restrict__ WT,
                                                     int K, int N) {
    __shared__ float t[32][33];
    size_t zoff = (size_t)blockIdx.z * K * N;
    const float* Wz = W + zoff;
    ushort* WTz = WT + zoff;
    int k0 = blockIdx.x * 32, n0 = blockIdx.y * 32;
    int tx = threadIdx.x, ty = threadIdx.y;
#pragma unroll
    for (int j = 0; j < 4; ++j)
        t[ty + j * 8][tx] = Wz[(size_t)(k0 + ty + j * 8) * N + n0 + tx];
    __syncthreads();
#pragma unroll
    for (int j = 0; j < 4; ++j)
        WTz[(size_t)(n0 + ty + j * 8) * K + k0 + tx] = f2bf(t[tx][ty + j * 8]);
}

// ---------------------------------------------------------------------------
// bf16 MFMA GEMM (m97 structure): C[M,N] = act(A[M,K] @ Bt[N,K]^T)
// 128x128 tile, BK=32, 4 waves (2x2), each wave 4x4 frags of 16x16x32 MFMA.
// A row-major bf16 with row stride lda. Bt row-major [N][K] bf16.
// ACT: 0 none, 1 elu+1, 2 relu.  OUTB: 0 -> fp32 Cf, 1 -> bf16 Cb.
// ---------------------------------------------------------------------------
template <int ACT, int OUTB>
__global__ __launch_bounds__(256) void gemm_bf16(const ushort* __restrict__ A, int lda,
                                                 const ushort* __restrict__ Bt,
                                                 float* __restrict__ Cf,
                                                 ushort* __restrict__ Cb,
                                                 int N, int K) {
    __shared__ ushort As[4096];  // [128][32]
    __shared__ ushort Bs[4096];  // [128][32]
    int tid = threadIdx.x;
    int m0 = blockIdx.x * 128, n0 = blockIdx.y * 128;
    int wave = tid >> 6, lane = tid & 63;
    int wm = (wave >> 1) * 64, wn = (wave & 1) * 64;
    int fm = lane & 15, kg = lane >> 4;

    f32x4 acc[4][4] = {};

    for (int k0 = 0; k0 < K; k0 += 32) {
        const ushort* Ag = A + (size_t)m0 * lda + k0;
        const ushort* Bg = Bt + (size_t)n0 * K + k0;
#pragma unroll
        for (int iss = 0; iss < 2; ++iss) {
            int slot = iss * 256 + tid;
            int rr = slot >> 2, cc = (slot & 3) * 8;
            __builtin_amdgcn_global_load_lds(
                (const __attribute__((address_space(1))) void*)(Ag + (size_t)rr * lda + cc),
                (__attribute__((address_space(3))) void*)(As + iss * 2048 + wave * 512),
                16, 0, 0);
            __builtin_amdgcn_global_load_lds(
                (const __attribute__((address_space(1))) void*)(Bg + (size_t)rr * K + cc),
                (__attribute__((address_space(3))) void*)(Bs + iss * 2048 + wave * 512),
                16, 0, 0);
        }
        __syncthreads();
        bf16x8 afr[4], bfr[4];
#pragma unroll
        for (int i = 0; i < 4; ++i)
            afr[i] = *(const bf16x8*)(As + (wm + i * 16 + fm) * 32 + kg * 8);
#pragma unroll
        for (int j = 0; j < 4; ++j)
            bfr[j] = *(const bf16x8*)(Bs + (wn + j * 16 + fm) * 32 + kg * 8);
#pragma unroll
        for (int i = 0; i < 4; ++i)
#pragma unroll
            for (int j = 0; j < 4; ++j)
                acc[i][j] = __builtin_amdgcn_mfma_f32_16x16x32_bf16(afr[i], bfr[j], acc[i][j], 0, 0, 0);
        __syncthreads();
    }

#pragma unroll
    for (int i = 0; i < 4; ++i) {
        int grow0 = m0 + wm + i * 16 + kg * 4;
#pragma unroll
        for (int r = 0; r < 4; ++r) {
            size_t rowoff = (size_t)(grow0 + r) * N;
#pragma unroll
            for (int j = 0; j < 4; ++j) {
                float v = acc[i][j][r];
                if (ACT == 1) v = elu1(v);
                if (ACT == 2) v = fmaxf(v, 0.f);
                int col = n0 + wn + j * 16 + fm;
                if (OUTB)
                    Cb[rowoff + col] = f2bf(v);
                else
                    Cf[rowoff + col] = v;
            }
        }
    }
}

__global__ void zero_kernel(float* __restrict__ p, int n) {
    int i = blockIdx.x * 256 + threadIdx.x;
    if (i < n) p[i] = 0.f;
}

// ---------------------------------------------------------------------------
// KV[b,h,d,v] = sum_s K[b,s,h,d]*V[b,s,h,v];  KS[b,h,d] = sum_s K[b,s,h,d]
// K, V are bf16. Partial sums over s-chunks, atomic combine (KV zeroed first).
// ---------------------------------------------------------------------------
__global__ __launch_bounds__(256) void kv_kernel(const ushort* __restrict__ Kf,
                                                 const ushort* __restrict__ Vf,
                                                 float* __restrict__ KV,
                                                 float* __restrict__ KS) {
    __shared__ float Ks[64][36];
    __shared__ float Vs[64][36];
    int tid = threadIdx.x;
    int bh = blockIdx.x;
    int sp = blockIdx.y;
    int b = bh >> 3, h = bh & 7;
    int d = tid >> 3, vb = (tid & 7) * 4;
    float acc0 = 0.f, acc1 = 0.f, acc2 = 0.f, acc3 = 0.f;
    float ksacc = 0.f;
    for (int s0 = sp * 512; s0 < sp * 512 + 512; s0 += 64) {
        for (int i = tid; i < 512; i += 256) {
            int r = i >> 3, c = (i & 7) * 4;
            size_t off = ((size_t)(b * LTOT + s0 + r)) * DM + h * 32 + c;
            ushort4 k4 = *(const ushort4*)(Kf + off);
            ushort4 v4 = *(const ushort4*)(Vf + off);
            Ks[r][c + 0] = b2f(k4.x); Ks[r][c + 1] = b2f(k4.y);
            Ks[r][c + 2] = b2f(k4.z); Ks[r][c + 3] = b2f(k4.w);
            Vs[r][c + 0] = b2f(v4.x); Vs[r][c + 1] = b2f(v4.y);
            Vs[r][c + 2] = b2f(v4.z); Vs[r][c + 3] = b2f(v4.w);
        }
        __syncthreads();
#pragma unroll 8
        for (int s = 0; s < 64; ++s) {
            float kd = Ks[s][d];
            acc0 += kd * Vs[s][vb + 0];
            acc1 += kd * Vs[s][vb + 1];
            acc2 += kd * Vs[s][vb + 2];
            acc3 += kd * Vs[s][vb + 3];
        }
        if (tid < 32) {
#pragma unroll 8
            for (int s = 0; s < 64; ++s) ksacc += Ks[s][tid];
        }
        __syncthreads();
    }
    float* kvp = KV + (size_t)bh * 1024 + d * 32 + vb;
    atomicAdd(kvp + 0, acc0);
    atomicAdd(kvp + 1, acc1);
    atomicAdd(kvp + 2, acc2);
    atomicAdd(kvp + 3, acc3);
    if (tid < 32) atomicAdd(KS + bh * 32 + tid, ksacc);
}

// ---------------------------------------------------------------------------
// msg[b,l,h,v] = (sum_d Q*KV) / (sum_d Q*KS + eps); Q fp32, msg out bf16
// ---------------------------------------------------------------------------
__global__ __launch_bounds__(256) void msg_kernel(const float* __restrict__ Q,
                                                  const float* __restrict__ KV,
                                                  const float* __restrict__ KS,
                                                  ushort* __restrict__ Msgb) {
    __shared__ float KVs[8 * 1032];
    __shared__ float KSs[256];
    int tid = threadIdx.x;
    int b = blockIdx.y;
    int l0 = blockIdx.x * 32;
    for (int i = tid; i < 8192; i += 256) {
        int h = i >> 10, r = i & 1023;
        KVs[h * 1032 + r] = KV[((size_t)(b * 8 + h)) * 1024 + r];
    }
    KSs[tid] = KS[b * 256 + tid];
    __syncthreads();
    int l = l0 + (tid >> 3);
    int h = tid & 7;
    const float* qp = Q + ((size_t)(b * LTOT + l)) * DM + h * 32;
    float qv[32];
#pragma unroll
    for (int i = 0; i < 8; ++i) {
        float4 q4 = *(const float4*)(qp + i * 4);
        qv[i * 4 + 0] = q4.x; qv[i * 4 + 1] = q4.y;
        qv[i * 4 + 2] = q4.z; qv[i * 4 + 3] = q4.w;
    }
    float den = 1e-6f;
#pragma unroll
    for (int d2 = 0; d2 < 32; ++d2) den += qv[d2] * KSs[h * 32 + d2];
    float rz = 1.f / den;
    float acc[32] = {};
#pragma unroll
    for (int d2 = 0; d2 < 32; ++d2) {
        float qd = qv[d2];
        const float* kvp = &KVs[h * 1032 + d2 * 32];
#pragma unroll
        for (int v = 0; v < 32; ++v) acc[v] += qd * kvp[v];
    }
    ushort* op = Msgb + ((size_t)(b * LTOT + l)) * DM + h * 32;
#pragma unroll
    for (int i = 0; i < 8; ++i) {
        ushort4 o4;
        o4.x = f2bf(acc[i * 4 + 0] * rz);
        o4.y = f2bf(acc[i * 4 + 1] * rz);
        o4.z = f2bf(acc[i * 4 + 2] * rz);
        o4.w = f2bf(acc[i * 4 + 3] * rz);
        *(ushort4*)(op + i * 4) = o4;
    }
}

// ---------------------------------------------------------------------------
// LayerNorm over 256. MODE 0: XC[row*512+256+c] = bf16(LN(In))   (LN1)
//                     MODE 1: X += LN(In); XC[row*512+c] = bf16(X)  (LN2+res)
// ---------------------------------------------------------------------------
template <int MODE>
__global__ __launch_bounds__(256) void ln_kernel(const float* __restrict__ In,
                                                 const float* __restrict__ g,
                                                 const float* __restrict__ bta,
                                                 float* __restrict__ X,
                                                 ushort* __restrict__ XC) {
    int row = blockIdx.x * 4 + (threadIdx.x >> 6);
    int lane = threadIdx.x & 63;
    int c = lane * 4;
    const float* p = In + (size_t)row * DM + c;
    float4 v = *(const float4*)p;
    float s = v.x + v.y + v.z + v.w;
#pragma unroll
    for (int o = 1; o < 64; o <<= 1) s += __shfl_xor(s, o, 64);
    float mu = s * (1.f / 256.f);
    float dx = v.x - mu, dy = v.y - mu, dz = v.z - mu, dw = v.w - mu;
    float sq = dx * dx + dy * dy + dz * dz + dw * dw;
#pragma unroll
    for (int o = 1; o < 64; o <<= 1) sq += __shfl_xor(sq, o, 64);
    float rstd = rsqrtf(sq * (1.f / 256.f) + 1e-5f);
    float4 gv = *(const float4*)(g + c);
    float4 bv = *(const float4*)(bta + c);
    float4 o4;
    o4.x = dx * rstd * gv.x + bv.x;
    o4.y = dy * rstd * gv.y + bv.y;
    o4.z = dz * rstd * gv.z + bv.z;
    o4.w = dw * rstd * gv.w + bv.w;
    if (MODE == 0) {
        ushort4 ob;
        ob.x = f2bf(o4.x); ob.y = f2bf(o4.y); ob.z = f2bf(o4.z); ob.w = f2bf(o4.w);
        *(ushort4*)(XC + (size_t)row * 512 + 256 + c) = ob;
    } else {
        float* xp = X + (size_t)row * DM + c;
        float4 x4 = *(const float4*)xp;
        x4.x += o4.x; x4.y += o4.y; x4.z += o4.z; x4.w += o4.w;
        *(float4*)xp = x4;
        ushort4 ob;
        ob.x = f2bf(x4.x); ob.y = f2bf(x4.y); ob.z = f2bf(x4.z); ob.w = f2bf(x4.w);
        *(ushort4*)(XC + (size_t)row * 512 + c) = ob;
    }
}

// ---------------------------------------------------------------------------
// Orchestration
// ---------------------------------------------------------------------------
extern "C" void kernel_launch(void* const* d_in, const int* in_sizes, int n_in,
                              void* d_out, int out_size, void* d_ws, size_t ws_size,
                              hipStream_t stream) {
    const float* feats = (const float*)d_in[0];
    const float* Wq = (const float*)d_in[1];
    const float* Wk = (const float*)d_in[2];
    const float* Wv = (const float*)d_in[3];
    const float* Wm = (const float*)d_in[4];
    const float* W1 = (const float*)d_in[5];
    const float* W2 = (const float*)d_in[6];
    const float* g1 = (const float*)d_in[7];
    const float* b1 = (const float*)d_in[8];
    const float* g2 = (const float*)d_in[9];
    const float* b2 = (const float*)d_in[10];

    // workspace: exactly 4*NX floats
    float* ws = (float*)d_ws;
    float* X = ws;                       // fp32 residual stream
    float* S1 = ws + NX;                 // fp32: Q -> msg@Wm -> mlp2-out
    float* S2f = ws + 2 * NX;            // bf16 double-duty region
    ushort* XC = (ushort*)(ws + 3 * NX); // [32768][512] bf16: [x | LN1(msg)]
    ushort* S2u = (ushort*)S2f;
    ushort* Kb = S2u;                    // [32768][256] bf16 K
    ushort* msgb = S2u + NX;             // [32768][256] bf16 msg
    ushort* HBb = S2u;                   // [32768][512] bf16 mlp hidden (after K/msg dead)

    // d_out doubles as scratch until the final unprep
    float* dout = (float*)d_out;
    ushort* Vb = (ushort*)dout;          // [32768][256] bf16 V (16 MB)
    ushort* WB = (ushort*)dout + NX;     // transposed bf16 weights (5 MB)
    float* KV = dout + (NX + 2621440) / 2;  // 65536 floats
    float* KS = KV + 65536;                 // 2048 floats

    ushort* WTq = WB;
    ushort* WTk = WB + 4 * 65536;
    ushort* WTv = WB + 8 * 65536;
    ushort* WTm = WB + 12 * 65536;
    ushort* WT1 = WB + 16 * 65536;
    ushort* WT2 = WB + 16 * 65536 + 4 * 262144;

    dim3 tblk(32, 8);
    wtrans_kernel<<<dim3(8, 8, 4), tblk, 0, stream>>>(Wq, WTq, 256, 256);
    wtrans_kernel<<<dim3(8, 8, 4), tblk, 0, stream>>>(Wk, WTk, 256, 256);
    wtrans_kernel<<<dim3(8, 8, 4), tblk, 0, stream>>>(Wv, WTv, 256, 256);
    wtrans_kernel<<<dim3(8, 8, 4), tblk, 0, stream>>>(Wm, WTm, 256, 256);
    wtrans_kernel<<<dim3(16, 16, 4), tblk, 0, stream>>>(W1, WT1, 512, 512);
    wtrans_kernel<<<dim3(16, 8, 4), tblk, 0, stream>>>(W2, WT2, 512, 256);

    prep_kernel<<<dim3(128, 8, 8), tblk, 0, stream>>>(feats, X, XC);

    dim3 gn256(256, 2), gn512(256, 4);

    for (int layer = 0; layer < 4; ++layer) {
        const ushort* wtq = WTq + (size_t)layer * 65536;
        const ushort* wtk = WTk + (size_t)layer * 65536;
        const ushort* wtv = WTv + (size_t)layer * 65536;
        const ushort* wtm = WTm + (size_t)layer * 65536;
        const ushort* wt1 = WT1 + (size_t)layer * 262144;
        const ushort* wt2 = WT2 + (size_t)layer * 131072;
        const float* lg1 = g1 + layer * DM;
        const float* lb1 = b1 + layer * DM;
        const float* lg2 = g2 + layer * DM;
        const float* lb2 = b2 + layer * DM;

        gemm_bf16<1, 0><<<gn256, 256, 0, stream>>>(XC, 512, wtq, S1, nullptr, 256, 256);  // Q fp32
        gemm_bf16<1, 1><<<gn256, 256, 0, stream>>>(XC, 512, wtk, nullptr, Kb, 256, 256);  // K bf16
        gemm_bf16<0, 1><<<gn256, 256, 0, stream>>>(XC, 512, wtv, nullptr, Vb, 256, 256);  // V bf16
        zero_kernel<<<dim3((67584 + 255) / 256), 256, 0, stream>>>(KV, 67584);
        kv_kernel<<<dim3(64, 8), 256, 0, stream>>>(Kb, Vb, KV, KS);
        msg_kernel<<<dim3(128, 8), 256, 0, stream>>>(S1, KV, KS, msgb);                   // msg bf16
        gemm_bf16<0, 0><<<gn256, 256, 0, stream>>>(msgb, 256, wtm, S1, nullptr, 256, 256);
        ln_kernel<0><<<8192, 256, 0, stream>>>(S1, lg1, lb1, nullptr, XC);                // XC right = LN1
        gemm_bf16<2, 1><<<gn512, 256, 0, stream>>>(XC, 512, wt1, nullptr, HBb, 512, 512); // relu MLP1
        gemm_bf16<0, 0><<<gn256, 256, 0, stream>>>(HBb, 512, wt2, S1, nullptr, 256, 512); // MLP2
        ln_kernel<1><<<8192, 256, 0, stream>>>(S1, lg2, lb2, X, XC);                      // X += LN2; XC left
    }

    unprep_kernel<<<dim3(128, 8, 8), tblk, 0, stream>>>(X, dout);
}

// Round 3
// 782.071 us; speedup vs baseline: 3.8991x; 1.0997x over previous
//
#include <hip/hip_runtime.h>
#include <hip/hip_bf16.h>

#define LTOT 4096
#define DM 256
#define BATCH 8
#define MROWS (BATCH * LTOT)     // 32768
#define NX ((size_t)MROWS * DM)  // 8388608 elements

typedef __bf16 bf16x8 __attribute__((ext_vector_type(8)));
typedef float f32x4 __attribute__((ext_vector_type(4)));

__device__ __forceinline__ float elu1(float x) {
    return x > 0.f ? x + 1.f : expf(x);
}
__device__ __forceinline__ ushort f2bf(float f) {
    unsigned u = __float_as_uint(f);
    u += 0x7FFFu + ((u >> 16) & 1u);
    return (ushort)(u >> 16);
}
__device__ __forceinline__ float b2f(ushort u) {
    return __uint_as_float(((unsigned)u) << 16);
}

// ---------------------------------------------------------------------------
// prep: X[b,l,c] = feats[b,c,l] + pos(c,l) (fp32); XC left half = bf16(same)
// ---------------------------------------------------------------------------
__global__ __launch_bounds__(256) void prep_kernel(const float* __restrict__ feats,
                                                   float* __restrict__ X,
                                                   ushort* __restrict__ XC) {
    __shared__ float tile[32][33];
    int b = blockIdx.z;
    int l0 = blockIdx.x * 32;
    int c0 = blockIdx.y * 32;
    int tx = threadIdx.x, ty = threadIdx.y;
#pragma unroll
    for (int j = 0; j < 4; ++j) {
        int c = c0 + ty + j * 8;
        tile[ty + j * 8][tx] = feats[((size_t)(b * DM + c)) * LTOT + l0 + tx];
    }
    __syncthreads();
#pragma unroll
    for (int j = 0; j < 4; ++j) {
        int l = l0 + ty + j * 8;
        int c = c0 + tx;
        int i2 = (c >> 2) * 2;
        float dv = expf((float)i2 * -0.07195578415156063f);
        int rem = c & 3;
        int y = l >> 6, xc = l & 63;
        float pos = (rem < 2) ? (float)(xc + 1) : (float)(y + 1);
        float arg = pos * dv;
        float pe = (rem & 1) ? cosf(arg) : sinf(arg);
        float val = tile[tx][ty + j * 8] + pe;
        size_t row = (size_t)(b * LTOT + l);
        X[row * DM + c] = val;
        XC[row * 512 + c] = f2bf(val);
    }
}

__global__ __launch_bounds__(256) void unprep_kernel(const float* __restrict__ X,
                                                     float* __restrict__ out) {
    __shared__ float tile[32][33];
    int b = blockIdx.z;
    int l0 = blockIdx.x * 32;
    int c0 = blockIdx.y * 32;
    int tx = threadIdx.x, ty = threadIdx.y;
#pragma unroll
    for (int j = 0; j < 4; ++j) {
        int l = l0 + ty + j * 8;
        tile[ty + j * 8][tx] = X[((size_t)(b * LTOT + l)) * DM + c0 + tx];
    }
    __syncthreads();
#pragma unroll
    for (int j = 0; j < 4; ++j) {
        int c = c0 + ty + j * 8;
        out[((size_t)(b * DM + c)) * LTOT + l0 + tx] = tile[tx][ty + j * 8];
    }
}

// ---------------------------------------------------------------------------
// weight transpose + bf16 cast with independent in/out layer strides:
// WT[n][k] = bf16(W[k][n]), z = layer
// ---------------------------------------------------------------------------
__global__ __launch_bounds__(256) void wtrans_kernel(const float* __restrict__ W,
                                                     ushort* __restrict__ WT,
                                                     int K, int N,
                                                     size_t in_ls, size_t out_ls) {
    __shared__ float t[32][33];
    const float* Wz = W + (size_t)blockIdx.z * in_ls;
    ushort* WTz = WT + (size_t)blockIdx.z * out_ls;
    int k0 = blockIdx.x * 32, n0 = blockIdx.y * 32;
    int tx = threadIdx.x, ty = threadIdx.y;
#pragma unroll
    for (int j = 0; j < 4; ++j)
        t[ty + j * 8][tx] = Wz[(size_t)(k0 + ty + j * 8) * N + n0 + tx];
    __syncthreads();
#pragma unroll
    for (int j = 0; j < 4; ++j)
        WTz[(size_t)(n0 + ty + j * 8) * K + k0 + tx] = f2bf(t[tx][ty + j * 8]);
}

// ---------------------------------------------------------------------------
// bf16 MFMA GEMM: Cb[M,N] = act(A[M,K] @ Bt[N,K]^T), bf16 out.
// 128x128 tile, BK=32, 4 waves 2x2, 4x4 frags of 16x16x32.
// ACT: 2 relu, 3 elu+1 for col<512 else identity (QKV).
// ---------------------------------------------------------------------------
template <int ACT>
__global__ __launch_bounds__(256) void gemm_bf16(const ushort* __restrict__ A, int lda,
                                                 const ushort* __restrict__ Bt,
                                                 ushort* __restrict__ Cb,
                                                 int N, int K) {
    __shared__ ushort As[4096];  // [128][32]
    __shared__ ushort Bs[4096];  // [128][32]
    int tid = threadIdx.x;
    int m0 = blockIdx.x * 128, n0 = blockIdx.y * 128;
    int wave = tid >> 6, lane = tid & 63;
    int wm = (wave >> 1) * 64, wn = (wave & 1) * 64;
    int fm = lane & 15, kg = lane >> 4;

    f32x4 acc[4][4] = {};

    for (int k0 = 0; k0 < K; k0 += 32) {
        const ushort* Ag = A + (size_t)m0 * lda + k0;
        const ushort* Bg = Bt + (size_t)n0 * K + k0;
#pragma unroll
        for (int iss = 0; iss < 2; ++iss) {
            int slot = iss * 256 + tid;
            int rr = slot >> 2, cc = (slot & 3) * 8;
            __builtin_amdgcn_global_load_lds(
                (const __attribute__((address_space(1))) void*)(Ag + (size_t)rr * lda + cc),
                (__attribute__((address_space(3))) void*)(As + iss * 2048 + wave * 512),
                16, 0, 0);
            __builtin_amdgcn_global_load_lds(
                (const __attribute__((address_space(1))) void*)(Bg + (size_t)rr * K + cc),
                (__attribute__((address_space(3))) void*)(Bs + iss * 2048 + wave * 512),
                16, 0, 0);
        }
        __syncthreads();
        bf16x8 afr[4], bfr[4];
#pragma unroll
        for (int i = 0; i < 4; ++i)
            afr[i] = *(const bf16x8*)(As + (wm + i * 16 + fm) * 32 + kg * 8);
#pragma unroll
        for (int j = 0; j < 4; ++j)
            bfr[j] = *(const bf16x8*)(Bs + (wn + j * 16 + fm) * 32 + kg * 8);
#pragma unroll
        for (int i = 0; i < 4; ++i)
#pragma unroll
            for (int j = 0; j < 4; ++j)
                acc[i][j] = __builtin_amdgcn_mfma_f32_16x16x32_bf16(afr[i], bfr[j], acc[i][j], 0, 0, 0);
        __syncthreads();
    }

#pragma unroll
    for (int i = 0; i < 4; ++i) {
        int grow0 = m0 + wm + i * 16 + kg * 4;
#pragma unroll
        for (int r = 0; r < 4; ++r) {
            size_t rowoff = (size_t)(grow0 + r) * N;
#pragma unroll
            for (int j = 0; j < 4; ++j) {
                float v = acc[i][j][r];
                int col = n0 + wn + j * 16 + fm;
                if (ACT == 2) v = fmaxf(v, 0.f);
                if (ACT == 3) v = (col < 512) ? elu1(v) : v;
                Cb[rowoff + col] = f2bf(v);
            }
        }
    }
}

// ---------------------------------------------------------------------------
// Fused GEMM + LayerNorm: T = A[M,K] @ Bt[256,K]^T; per-row LN over 256.
// Tile 128 rows x 256 cols (full width), 512 threads = 8 waves (2 x 4).
// RES=0 (LN1):  XC[row*512 + 256 + col] = bf16(LN(T))
// RES=1 (LN2):  X[row][col] += LN(T); XC[row*512 + col] = bf16(X)
// ---------------------------------------------------------------------------
template <int RES>
__global__ __launch_bounds__(512) void gemm_ln(const ushort* __restrict__ A, int lda,
                                               const ushort* __restrict__ Bt, int K,
                                               const float* __restrict__ g,
                                               const float* __restrict__ bta,
                                               float* __restrict__ X,
                                               ushort* __restrict__ XC) {
    __shared__ ushort As[4096];   // [128][32]
    __shared__ ushort Bs[8192];   // [256][32]
    __shared__ float red[128 * 8];
    __shared__ float musig[128 * 2];
    int tid = threadIdx.x;
    int m0 = blockIdx.x * 128;
    int wave = tid >> 6, lane = tid & 63;
    int wr = wave >> 2, wc = wave & 3;
    int fm = lane & 15, kg = lane >> 4;

    f32x4 acc[4][4] = {};

    for (int k0 = 0; k0 < K; k0 += 32) {
        const ushort* Ag = A + (size_t)m0 * lda + k0;
        const ushort* Bg = Bt + k0;
        {
            int rr = tid >> 2, cc = (tid & 3) * 8;
            __builtin_amdgcn_global_load_lds(
                (const __attribute__((address_space(1))) void*)(Ag + (size_t)rr * lda + cc),
                (__attribute__((address_space(3))) void*)(As + wave * 512),
                16, 0, 0);
        }
#pragma unroll
        for (int iss = 0; iss < 2; ++iss) {
            int slot = iss * 512 + tid;
            int rr = slot >> 2, cc = (slot & 3) * 8;
            __builtin_amdgcn_global_load_lds(
                (const __attribute__((address_space(1))) void*)(Bg + (size_t)rr * K + cc),
                (__attribute__((address_space(3))) void*)(Bs + iss * 4096 + wave * 512),
                16, 0, 0);
        }
        __syncthreads();
        bf16x8 afr[4], bfr[4];
#pragma unroll
        for (int i = 0; i < 4; ++i)
            afr[i] = *(const bf16x8*)(As + (wr * 64 + i * 16 + fm) * 32 + kg * 8);
#pragma unroll
        for (int j = 0; j < 4; ++j)
            bfr[j] = *(const bf16x8*)(Bs + (wc * 64 + j * 16 + fm) * 32 + kg * 8);
#pragma unroll
        for (int i = 0; i < 4; ++i)
#pragma unroll
            for (int j = 0; j < 4; ++j)
                acc[i][j] = __builtin_amdgcn_mfma_f32_16x16x32_bf16(afr[i], bfr[j], acc[i][j], 0, 0, 0);
        __syncthreads();
    }

    // per-row partial sums (this wave covers 64 of the 256 cols)
#pragma unroll
    for (int i = 0; i < 4; ++i) {
#pragma unroll
        for (int r = 0; r < 4; ++r) {
            float s = acc[i][0][r] + acc[i][1][r] + acc[i][2][r] + acc[i][3][r];
            float q = acc[i][0][r] * acc[i][0][r] + acc[i][1][r] * acc[i][1][r] +
                      acc[i][2][r] * acc[i][2][r] + acc[i][3][r] * acc[i][3][r];
#pragma unroll
            for (int o = 1; o < 16; o <<= 1) {
                s += __shfl_xor(s, o, 64);
                q += __shfl_xor(q, o, 64);
            }
            if ((lane & 15) == 0) {
                int row = wr * 64 + i * 16 + kg * 4 + r;
                red[row * 8 + wc] = s;
                red[row * 8 + 4 + wc] = q;
            }
        }
    }
    __syncthreads();
    if (tid < 128) {
        float s = red[tid * 8 + 0] + red[tid * 8 + 1] + red[tid * 8 + 2] + red[tid * 8 + 3];
        float q = red[tid * 8 + 4] + red[tid * 8 + 5] + red[tid * 8 + 6] + red[tid * 8 + 7];
        float mu = s * (1.f / 256.f);
        float var = q * (1.f / 256.f) - mu * mu;
        musig[tid * 2] = mu;
        musig[tid * 2 + 1] = rsqrtf(var + 1e-5f);
    }
    __syncthreads();

    float gv[4], bv[4];
#pragma unroll
    for (int j = 0; j < 4; ++j) {
        int col = wc * 64 + j * 16 + fm;
        gv[j] = g[col];
        bv[j] = bta[col];
    }
#pragma unroll
    for (int i = 0; i < 4; ++i) {
#pragma unroll
        for (int r = 0; r < 4; ++r) {
            int rl = wr * 64 + i * 16 + kg * 4 + r;
            float mu = musig[rl * 2], rstd = musig[rl * 2 + 1];
            size_t grow = (size_t)(m0 + rl);
#pragma unroll
            for (int j = 0; j < 4; ++j) {
                int col = wc * 64 + j * 16 + fm;
                float v = (acc[i][j][r] - mu) * rstd * gv[j] + bv[j];
                if (RES) {
                    float x = X[grow * 256 + col] + v;
                    X[grow * 256 + col] = x;
                    XC[grow * 512 + col] = f2bf(x);
                } else {
                    XC[grow * 512 + 256 + col] = f2bf(v);
                }
            }
        }
    }
}

__global__ void zero_kernel(float* __restrict__ p, int n) {
    int i = blockIdx.x * 256 + threadIdx.x;
    if (i < n) p[i] = 0.f;
}

// ---------------------------------------------------------------------------
// KV[b,h,d,v] = sum_s K[b,s,h,d]*V[b,s,h,v];  KS[b,h,d] = sum_s K
// K, V bf16 with row stride `str`. Atomic combine over s-chunks.
// ---------------------------------------------------------------------------
__global__ __launch_bounds__(256) void kv_kernel(const ushort* __restrict__ Kf,
                                                 const ushort* __restrict__ Vf,
                                                 int str,
                                                 float* __restrict__ KV,
                                                 float* __restrict__ KS) {
    __shared__ float Ks[64][36];
    __shared__ float Vs[64][36];
    int tid = threadIdx.x;
    int bh = blockIdx.x;
    int sp = blockIdx.y;
    int b = bh >> 3, h = bh & 7;
    int d = tid >> 3, vb = (tid & 7) * 4;
    float acc0 = 0.f, acc1 = 0.f, acc2 = 0.f, acc3 = 0.f;
    float ksacc = 0.f;
    for (int s0 = sp * 512; s0 < sp * 512 + 512; s0 += 64) {
        for (int i = tid; i < 512; i += 256) {
            int r = i >> 3, c = (i & 7) * 4;
            size_t off = ((size_t)(b * LTOT + s0 + r)) * str + h * 32 + c;
            ushort4 k4 = *(const ushort4*)(Kf + off);
            ushort4 v4 = *(const ushort4*)(Vf + off);
            Ks[r][c + 0] = b2f(k4.x); Ks[r][c + 1] = b2f(k4.y);
            Ks[r][c + 2] = b2f(k4.z); Ks[r][c + 3] = b2f(k4.w);
            Vs[r][c + 0] = b2f(v4.x); Vs[r][c + 1] = b2f(v4.y);
            Vs[r][c + 2] = b2f(v4.z); Vs[r][c + 3] = b2f(v4.w);
        }
        __syncthreads();
#pragma unroll 8
        for (int s = 0; s < 64; ++s) {
            float kd = Ks[s][d];
            acc0 += kd * Vs[s][vb + 0];
            acc1 += kd * Vs[s][vb + 1];
            acc2 += kd * Vs[s][vb + 2];
            acc3 += kd * Vs[s][vb + 3];
        }
        if (tid < 32) {
#pragma unroll 8
            for (int s = 0; s < 64; ++s) ksacc += Ks[s][tid];
        }
        __syncthreads();
    }
    float* kvp = KV + (size_t)bh * 1024 + d * 32 + vb;
    atomicAdd(kvp + 0, acc0);
    atomicAdd(kvp + 1, acc1);
    atomicAdd(kvp + 2, acc2);
    atomicAdd(kvp + 3, acc3);
    if (tid < 32) atomicAdd(KS + bh * 32 + tid, ksacc);
}

// ---------------------------------------------------------------------------
// msg[b,l,h,v] = (sum_d Q*KV) / (sum_d Q*KS + eps); Q bf16 stride qstr
// ---------------------------------------------------------------------------
__global__ __launch_bounds__(256) void msg_kernel(const ushort* __restrict__ Qb, int qstr,
                                                  const float* __restrict__ KV,
                                                  const float* __restrict__ KS,
                                                  ushort* __restrict__ Msgb) {
    __shared__ float KVs[8 * 1032];
    __shared__ float KSs[256];
    int tid = threadIdx.x;
    int b = blockIdx.y;
    int l0 = blockIdx.x * 32;
    for (int i = tid; i < 8192; i += 256) {
        int h = i >> 10, r = i & 1023;
        KVs[h * 1032 + r] = KV[((size_t)(b * 8 + h)) * 1024 + r];
    }
    KSs[tid] = KS[b * 256 + tid];
    __syncthreads();
    int l = l0 + (tid >> 3);
    int h = tid & 7;
    const ushort* qp = Qb + ((size_t)(b * LTOT + l)) * qstr + h * 32;
    float qv[32];
#pragma unroll
    for (int i = 0; i < 8; ++i) {
        ushort4 q4 = *(const ushort4*)(qp + i * 4);
        qv[i * 4 + 0] = b2f(q4.x); qv[i * 4 + 1] = b2f(q4.y);
        qv[i * 4 + 2] = b2f(q4.z); qv[i * 4 + 3] = b2f(q4.w);
    }
    float den = 1e-6f;
#pragma unroll
    for (int d2 = 0; d2 < 32; ++d2) den += qv[d2] * KSs[h * 32 + d2];
    float rz = 1.f / den;
    float acc[32] = {};
#pragma unroll
    for (int d2 = 0; d2 < 32; ++d2) {
        float qd = qv[d2];
        const float* kvp = &KVs[h * 1032 + d2 * 32];
#pragma unroll
        for (int v = 0; v < 32; ++v) acc[v] += qd * kvp[v];
    }
    ushort* op = Msgb + ((size_t)(b * LTOT + l)) * DM + h * 32;
#pragma unroll
    for (int i = 0; i < 8; ++i) {
        ushort4 o4;
        o4.x = f2bf(acc[i * 4 + 0] * rz);
        o4.y = f2bf(acc[i * 4 + 1] * rz);
        o4.z = f2bf(acc[i * 4 + 2] * rz);
        o4.w = f2bf(acc[i * 4 + 3] * rz);
        *(ushort4*)(op + i * 4) = o4;
    }
}

// ---------------------------------------------------------------------------
// Orchestration
// ---------------------------------------------------------------------------
extern "C" void kernel_launch(void* const* d_in, const int* in_sizes, int n_in,
                              void* d_out, int out_size, void* d_ws, size_t ws_size,
                              hipStream_t stream) {
    const float* feats = (const float*)d_in[0];
    const float* Wq = (const float*)d_in[1];
    const float* Wk = (const float*)d_in[2];
    const float* Wv = (const float*)d_in[3];
    const float* Wm = (const float*)d_in[4];
    const float* W1 = (const float*)d_in[5];
    const float* W2 = (const float*)d_in[6];
    const float* g1 = (const float*)d_in[7];
    const float* b1 = (const float*)d_in[8];
    const float* g2 = (const float*)d_in[9];
    const float* b2 = (const float*)d_in[10];

    // workspace: 112 MB used
    float* ws = (float*)d_ws;
    float* X = ws;                            // fp32 residual [32768][256]
    ushort* XC = (ushort*)(ws + NX);          // bf16 [32768][512]: [x | LN1(msg)]
    ushort* QKVb = (ushort*)(ws + 2 * NX);    // bf16 [32768][768]; aliased by HBb
    ushort* HBb = QKVb;                       // bf16 [32768][512] MLP hidden

    // d_out doubles as scratch until the final unprep (32 MB)
    float* dout = (float*)d_out;
    ushort* msgb = (ushort*)dout;             // bf16 [32768][256] (16 MB)
    ushort* WB = (ushort*)dout + NX;
    ushort* WTqkv = WB;                       // [4][768][256]
    ushort* WTm = WB + 4 * 196608;            // [4][256][256]
    ushort* WT1 = WTm + 4 * 65536;            // [4][512][512]
    ushort* WT2 = WT1 + 4 * 262144;           // [4][256][512]
    float* KV = dout + (NX + 2621440) / 2;    // 65536 floats
    float* KS = KV + 65536;                   // 2048 floats

    dim3 tblk(32, 8);
    // QKV weights concatenated along n: rows [0,256)=Wq, [256,512)=Wk, [512,768)=Wv
    wtrans_kernel<<<dim3(8, 8, 4), tblk, 0, stream>>>(Wq, WTqkv, 256, 256, 65536, 196608);
    wtrans_kernel<<<dim3(8, 8, 4), tblk, 0, stream>>>(Wk, WTqkv + 65536, 256, 256, 65536, 196608);
    wtrans_kernel<<<dim3(8, 8, 4), tblk, 0, stream>>>(Wv, WTqkv + 131072, 256, 256, 65536, 196608);
    wtrans_kernel<<<dim3(8, 8, 4), tblk, 0, stream>>>(Wm, WTm, 256, 256, 65536, 65536);
    wtrans_kernel<<<dim3(16, 16, 4), tblk, 0, stream>>>(W1, WT1, 512, 512, 262144, 262144);
    wtrans_kernel<<<dim3(16, 8, 4), tblk, 0, stream>>>(W2, WT2, 512, 256, 131072, 131072);

    prep_kernel<<<dim3(128, 8, 8), tblk, 0, stream>>>(feats, X, XC);

    for (int layer = 0; layer < 4; ++layer) {
        const ushort* wtqkv = WTqkv + (size_t)layer * 196608;
        const ushort* wtm = WTm + (size_t)layer * 65536;
        const ushort* wt1 = WT1 + (size_t)layer * 262144;
        const ushort* wt2 = WT2 + (size_t)layer * 131072;
        const float* lg1 = g1 + layer * DM;
        const float* lb1 = b1 + layer * DM;
        const float* lg2 = g2 + layer * DM;
        const float* lb2 = b2 + layer * DM;

        // QKV fused: [32768][768] = elu1/elu1/id( XC[:, :256] @ [Wq|Wk|Wv] )
        gemm_bf16<3><<<dim3(256, 6), 256, 0, stream>>>(XC, 512, wtqkv, QKVb, 768, 256);
        zero_kernel<<<dim3((67584 + 255) / 256), 256, 0, stream>>>(KV, 67584);
        kv_kernel<<<dim3(64, 8), 256, 0, stream>>>(QKVb + 256, QKVb + 512, 768, KV, KS);
        msg_kernel<<<dim3(128, 8), 256, 0, stream>>>(QKVb, 768, KV, KS, msgb);
        // Wm GEMM + LN1 fused -> XC right half
        gemm_ln<0><<<256, 512, 0, stream>>>(msgb, 256, wtm, 256, lg1, lb1, nullptr, XC);
        // MLP1: relu( XC[:, :512] @ W1 ) -> HBb  (aliases QKVb, which is dead)
        gemm_bf16<2><<<dim3(256, 4), 256, 0, stream>>>(XC, 512, wt1, HBb, 512, 512);
        // MLP2 + LN2 + residual fused -> X, XC left half
        gemm_ln<1><<<256, 512, 0, stream>>>(HBb, 512, wt2, 512, lg2, lb2, X, XC);
    }

    unprep_kernel<<<dim3(128, 8, 8), tblk, 0, stream>>>(X, dout);
}